// Round 1
// baseline (358.079 us; speedup 1.0000x reference)
//
#include <hip/hip_runtime.h>
#include <hip/hip_bf16.h>
#include <math.h>

#define N_NODES 50000
#define N_EDGES 800000
#define IN_CH 128
#define OUT_CH 64
#define BN_EPS 1e-5f

// ---------------- init: deg = 1 (self loop), sums = 0 ----------------
__global__ void init_kernel(float* __restrict__ deg, float* __restrict__ sums, int N) {
    int i = blockIdx.x * blockDim.x + threadIdx.x;
    if (i < N) deg[i] = 1.0f;
    if (i < 128) sums[i] = 0.0f;
}

// ---------------- degree count over edge dst ----------------
__global__ void deg_count_kernel(const int* __restrict__ edst, float* __restrict__ deg, int E) {
    int i = blockIdx.x * blockDim.x + threadIdx.x;
    if (i < E) atomicAdd(&deg[edst[i]], 1.0f);
}

// ---------------- GEMM: h[N,64] = x[N,128] @ W[128,64] ----------------
// Block = 256 threads. W staged in LDS (32 KB), x tile of 16 rows (8 KB).
// Thread t: channel c = t&63, group g = t>>6 handles rows g*4..g*4+3.
__global__ __launch_bounds__(256) void gemm_kernel(const float* __restrict__ x,
                                                   const float* __restrict__ W,
                                                   float* __restrict__ h, int N) {
    __shared__ float Wlds[IN_CH * OUT_CH];   // 8192 floats = 32 KB
    __shared__ float xlds[16 * IN_CH];       // 2048 floats = 8 KB
    int t = threadIdx.x;
    // cooperative W load (2048 float4 / 256 threads = 8 each)
    const float4* W4 = (const float4*)W;
    float4* Wl4 = (float4*)Wlds;
#pragma unroll
    for (int i = 0; i < 8; ++i) Wl4[t + 256 * i] = W4[t + 256 * i];

    int c = t & 63;
    int g = t >> 6;  // wave index 0..3 (wave-uniform)

    for (int tile = blockIdx.x; tile < N / 16; tile += gridDim.x) {
        int row0 = tile * 16;
        __syncthreads();  // protect xlds reuse (also orders W load on first iter)
        const float4* xsrc = (const float4*)(x + (size_t)row0 * IN_CH);
        float4* xl4 = (float4*)xlds;
        xl4[t] = xsrc[t];
        xl4[t + 256] = xsrc[t + 256];
        __syncthreads();

        float acc0 = 0.f, acc1 = 0.f, acc2 = 0.f, acc3 = 0.f;
        const float4* xl4r = (const float4*)xlds;
#pragma unroll 4
        for (int k4 = 0; k4 < 32; ++k4) {
            float4 xv0 = xl4r[(g * 4 + 0) * 32 + k4];
            float4 xv1 = xl4r[(g * 4 + 1) * 32 + k4];
            float4 xv2 = xl4r[(g * 4 + 2) * 32 + k4];
            float4 xv3 = xl4r[(g * 4 + 3) * 32 + k4];
            const float* p0 = (const float*)&xv0;
            const float* p1 = (const float*)&xv1;
            const float* p2 = (const float*)&xv2;
            const float* p3 = (const float*)&xv3;
#pragma unroll
            for (int j = 0; j < 4; ++j) {
                float w = Wlds[(k4 * 4 + j) * OUT_CH + c];
                acc0 += p0[j] * w;
                acc1 += p1[j] * w;
                acc2 += p2[j] * w;
                acc3 += p3[j] * w;
            }
        }
        size_t base = (size_t)(row0 + g * 4) * OUT_CH + c;
        h[base + 0 * OUT_CH] = acc0;
        h[base + 1 * OUT_CH] = acc1;
        h[base + 2 * OUT_CH] = acc2;
        h[base + 3 * OUT_CH] = acc3;
    }
}

// ---------------- dinv = rsqrt(deg); agg = h * dinv^2 (self-loop term) ----------------
__global__ __launch_bounds__(256) void dinv_self_kernel(const float* __restrict__ deg,
                                                        float* __restrict__ dinv,
                                                        const float* __restrict__ h,
                                                        float* __restrict__ agg, int N) {
    int lane = threadIdx.x & 63;
    int wid = (blockIdx.x * blockDim.x + threadIdx.x) >> 6;
    int nw = (gridDim.x * blockDim.x) >> 6;
    for (int i = wid; i < N; i += nw) {
        float di = rsqrtf(deg[i]);
        if (lane == 0) dinv[i] = di;
        size_t off = (size_t)i * OUT_CH + lane;
        agg[off] = h[off] * di * di;
    }
}

// ---------------- edge scatter: wave per edge, lane = channel ----------------
__global__ __launch_bounds__(256) void edge_scatter_kernel(const int* __restrict__ esrc,
                                                           const int* __restrict__ edst,
                                                           const float* __restrict__ dinv,
                                                           const float* __restrict__ h,
                                                           float* __restrict__ agg, int E) {
    int lane = threadIdx.x & 63;
    int wid = (blockIdx.x * blockDim.x + threadIdx.x) >> 6;
    int nw = (gridDim.x * blockDim.x) >> 6;
    for (int e = wid; e < E; e += nw) {
        int s = esrc[e];
        int d = edst[e];
        float nrm = dinv[s] * dinv[d];
        float v = h[(size_t)s * OUT_CH + lane] * nrm;
        atomicAdd(&agg[(size_t)d * OUT_CH + lane], v);
    }
}

// ---------------- a = tanh(agg + bias); accumulate per-channel sum, sumsq ----------------
__global__ __launch_bounds__(256) void tanh_stats_kernel(float* __restrict__ a,
                                                         const float* __restrict__ bias,
                                                         float* __restrict__ sums, int N) {
    int t = threadIdx.x;
    int c = t & 63;
    float b = bias[c];
    float s = 0.f, s2 = 0.f;
    size_t total = (size_t)gridDim.x * blockDim.x;  // multiple of 64 -> channel stays fixed
    for (size_t idx = (size_t)blockIdx.x * blockDim.x + t; idx < (size_t)N * OUT_CH; idx += total) {
        float v = tanhf(a[idx] + b);
        a[idx] = v;
        s += v;
        s2 += v * v;
    }
    __shared__ float ls[256];
    __shared__ float ls2[256];
    ls[t] = s; ls2[t] = s2;
    __syncthreads();
    if (t < 128) { ls[t] += ls[t + 128]; ls2[t] += ls2[t + 128]; }
    __syncthreads();
    if (t < 64) {
        float ss = ls[t] + ls[t + 64];
        float ss2 = ls2[t] + ls2[t + 64];
        atomicAdd(&sums[c], ss);
        atomicAdd(&sums[64 + c], ss2);
    }
}

// ---------------- BN apply in place ----------------
__global__ __launch_bounds__(256) void bn_apply_kernel(float* __restrict__ a,
                                                       const float* __restrict__ sums,
                                                       const float* __restrict__ gamma,
                                                       const float* __restrict__ beta, int N) {
    int c = threadIdx.x & 63;
    const float invN = 1.0f / (float)N_NODES;
    float mean = sums[c] * invN;
    float var = sums[64 + c] * invN - mean * mean;
    float scale = gamma[c] * rsqrtf(var + BN_EPS);
    float shift = beta[c] - mean * scale;
    size_t total = (size_t)gridDim.x * blockDim.x;
    for (size_t idx = (size_t)blockIdx.x * blockDim.x + threadIdx.x; idx < (size_t)N * OUT_CH; idx += total) {
        a[idx] = a[idx] * scale + shift;
    }
}

extern "C" void kernel_launch(void* const* d_in, const int* in_sizes, int n_in,
                              void* d_out, int out_size, void* d_ws, size_t ws_size,
                              hipStream_t stream) {
    const float* x     = (const float*)d_in[0];
    const int*   eidx  = (const int*)d_in[1];   // [2, E] flat: src then dst
    const float* W     = (const float*)d_in[2];
    const float* bias  = (const float*)d_in[3];
    const float* gamma = (const float*)d_in[4];
    const float* beta  = (const float*)d_in[5];
    float* out = (float*)d_out;  // used as agg / a buffer, fully overwritten

    const int* esrc = eidx;
    const int* edst = eidx + N_EDGES;

    // workspace layout (floats): h[3.2M], deg[50k], dinv[50k], sums[128]
    float* h    = (float*)d_ws;
    float* deg  = h + (size_t)N_NODES * OUT_CH;
    float* dinv = deg + N_NODES;
    float* sums = dinv + N_NODES;

    init_kernel<<<(N_NODES + 255) / 256, 256, 0, stream>>>(deg, sums, N_NODES);
    deg_count_kernel<<<(N_EDGES + 255) / 256, 256, 0, stream>>>(edst, deg, N_EDGES);
    gemm_kernel<<<N_NODES / 16, 256, 0, stream>>>(x, W, h, N_NODES);
    dinv_self_kernel<<<N_NODES / 4, 256, 0, stream>>>(deg, dinv, h, out, N_NODES);
    edge_scatter_kernel<<<16384, 256, 0, stream>>>(esrc, edst, dinv, h, out, N_EDGES);
    tanh_stats_kernel<<<512, 256, 0, stream>>>(out, bias, sums, N_NODES);
    bn_apply_kernel<<<512, 256, 0, stream>>>(out, sums, gamma, beta, N_NODES);
}